// Round 1
// baseline (297.840 us; speedup 1.0000x reference)
//
#include <hip/hip_runtime.h>
#include <stdint.h>

// SimCLR clear loss, MI355X.
// Pipeline:
//   1. cast_kernel:    out fp32[8192x512] -> f16 in ws
//   2. gemm_denom:     fused  exp(X.X^T/T) masked row-sum -> denom[8192] (atomics)
//   3. pos_kernel:     -sum(dot(out1_i,out2_i))/ (T*B) ... folded scale -> d_out
//   4. logdenom:       + mean(log(denom)) -> d_out
// d_out[0] = mean(log denom) - mean(log pos)

#define NROWS 8192
#define DIM   512

typedef _Float16 f16x8 __attribute__((ext_vector_type(8)));
typedef _Float16 f16x4 __attribute__((ext_vector_type(4)));
typedef float    f32x4 __attribute__((ext_vector_type(4)));

__device__ __forceinline__ void load16_g2l(void* lds, const void* g) {
    // CK-style address-space casts (uintptr_t round-trip keeps reinterpret_cast legal).
    auto* l3 = reinterpret_cast<__attribute__((address_space(3))) uint32_t*>(
        reinterpret_cast<uintptr_t>(lds));
    auto* g1 = reinterpret_cast<const __attribute__((address_space(1))) uint32_t*>(
        reinterpret_cast<uintptr_t>(g));
    __builtin_amdgcn_global_load_lds(g1, l3, 16, 0, 0);
}

// ---------------- 1. fp32 -> f16 cast ----------------
__global__ __launch_bounds__(256) void cast_kernel(const float* __restrict__ x,
                                                   _Float16* __restrict__ y) {
    int i = (blockIdx.x * 256 + threadIdx.x) * 4;
    float4 v = *(const float4*)(x + i);
    f16x4 h;
    h[0] = (_Float16)v.x; h[1] = (_Float16)v.y;
    h[2] = (_Float16)v.z; h[3] = (_Float16)v.w;
    *(f16x4*)(y + i) = h;
}

// ---------------- 2. fused GEMM + exp + mask + row-sum ----------------
// Tile 128x128, BK=64, 4 waves (2x2 of 64x64), 16x16x32 f16 MFMA.
// LDS layout is fragment-ordered: [kk2][rowgroup][lane] 16B chunks, so
// ds_read_b128 of a fragment is 64 consecutive chunks (conflict-free) and
// global_load_lds (wave-uniform base + lane*16) lands each lane's gather
// exactly where the fragment read expects it.
__global__ __launch_bounds__(256) void gemm_denom_kernel(const _Float16* __restrict__ X,
                                                         const int* __restrict__ labels,
                                                         float* __restrict__ denom) {
    __shared__ __align__(16) _Float16 Atile[8192];  // 16 KiB: [2][8][64][8]
    __shared__ __align__(16) _Float16 Btile[8192];

    const int tid  = threadIdx.x;
    const int lane = tid & 63;
    const int wv   = tid >> 6;
    const int bm   = blockIdx.y * 128;
    const int bn   = blockIdx.x * 128;
    const int lc   = lane & 15;
    const int l8   = (lane >> 4) * 8;

    f32x4 acc[4][4] = {};

    for (int kb = 0; kb < DIM; kb += 64) {
        __syncthreads();  // protect LDS from previous iteration's readers
        // ---- stage A (groups 0..15) and B (groups 16..31), 8 loads/thread ----
        #pragma unroll
        for (int g = 0; g < 8; ++g) {
            int grp  = wv + g * 4;            // wave-uniform
            int idx  = grp & 15;
            int kk2  = idx >> 3;
            int rg   = idx & 7;
            int row  = (grp < 16 ? bm : bn) + rg * 16 + lc;
            int kcol = kb + kk2 * 32 + l8;
            const _Float16* src = X + (size_t)row * DIM + kcol;
            _Float16* dst = (grp < 16 ? Atile : Btile) + ((kk2 * 8 + rg) * 64 + lane) * 8;
            load16_g2l(dst, src);
        }
        __syncthreads();  // drains vmcnt(0): staged data visible

        const int rga = (wv >> 1) * 4;
        const int rgb = (wv & 1) * 4;
        #pragma unroll
        for (int kk2 = 0; kk2 < 2; ++kk2) {
            f16x8 af[4], bf[4];
            #pragma unroll
            for (int t = 0; t < 4; ++t)
                af[t] = *(const f16x8*)&Atile[((kk2 * 8 + rga + t) * 64 + lane) * 8];
            #pragma unroll
            for (int t = 0; t < 4; ++t)
                bf[t] = *(const f16x8*)&Btile[((kk2 * 8 + rgb + t) * 64 + lane) * 8];
            #pragma unroll
            for (int mt = 0; mt < 4; ++mt)
                #pragma unroll
                for (int nt = 0; nt < 4; ++nt)
                    acc[mt][nt] = __builtin_amdgcn_mfma_f32_16x16x32_f16(
                        af[mt], bf[nt], acc[mt][nt], 0, 0, 0);
        }
    }

    // ---- epilogue: exp2(acc * 2*log2e), mask, row-reduce, atomic ----
    // C/D layout: col = lane&15, row = (lane>>4)*4 + reg   [m89/m91 verified]
    const int row0 = bm + (wv >> 1) * 64;
    const int col0 = bn + (wv & 1) * 64;
    const int lq   = lane >> 4;
    int colLab[4];
    #pragma unroll
    for (int nt = 0; nt < 4; ++nt) colLab[nt] = labels[col0 + nt * 16 + lc];
    const float cs = 2.0f * 1.4426950408889634f;  // (1/T) * log2(e)

    #pragma unroll
    for (int mt = 0; mt < 4; ++mt) {
        #pragma unroll
        for (int r = 0; r < 4; ++r) {
            int grow = row0 + mt * 16 + lq * 4 + r;
            int rl = labels[grow];
            float s = 0.f;
            #pragma unroll
            for (int nt = 0; nt < 4; ++nt) {
                int gcol = col0 + nt * 16 + lc;
                float e = exp2f(acc[mt][nt][r] * cs);
                s += ((rl == colLab[nt]) && (grow != gcol)) ? e : 0.f;
            }
            #pragma unroll
            for (int d = 1; d < 16; d <<= 1) s += __shfl_xor(s, d, 64);
            if (lc == 0) atomicAdd(&denom[grow], s);
        }
    }
}

// ---------------- 3. positive-pair term ----------------
// loss -= (1/2B) * sum over 2B rows of log pos = (4/8192)*sum d_i = sum d_i/2048
__global__ __launch_bounds__(256) void pos_kernel(const float* __restrict__ o1,
                                                  const float* __restrict__ o2,
                                                  float* __restrict__ out) {
    const int lane = threadIdx.x & 63;
    const int wave = (blockIdx.x * 256 + threadIdx.x) >> 6;  // 0..511
    float s = 0.f;
    for (int r = wave; r < 4096; r += 512) {
        const float4* a = (const float4*)(o1 + (size_t)r * DIM);
        const float4* b = (const float4*)(o2 + (size_t)r * DIM);
        float4 va = a[lane], vb = b[lane];
        s += va.x * vb.x + va.y * vb.y + va.z * vb.z + va.w * vb.w;
        va = a[lane + 64]; vb = b[lane + 64];
        s += va.x * vb.x + va.y * vb.y + va.z * vb.z + va.w * vb.w;
    }
    #pragma unroll
    for (int d = 1; d < 64; d <<= 1) s += __shfl_xor(s, d, 64);
    __shared__ float red[4];
    if (lane == 0) red[threadIdx.x >> 6] = s;
    __syncthreads();
    if (threadIdx.x == 0)
        atomicAdd(out, -(red[0] + red[1] + red[2] + red[3]) * (1.0f / 2048.0f));
}

// ---------------- 4. mean(log(denom)) ----------------
__global__ __launch_bounds__(256) void logdenom_kernel(const float* __restrict__ denom,
                                                       float* __restrict__ out) {
    int i = blockIdx.x * 256 + threadIdx.x;
    float v = __logf(denom[i]) * (1.0f / 8192.0f);
    #pragma unroll
    for (int d = 1; d < 64; d <<= 1) v += __shfl_xor(v, d, 64);
    __shared__ float red[4];
    if ((threadIdx.x & 63) == 0) red[threadIdx.x >> 6] = v;
    __syncthreads();
    if (threadIdx.x == 0) atomicAdd(out, red[0] + red[1] + red[2] + red[3]);
}

extern "C" void kernel_launch(void* const* d_in, const int* in_sizes, int n_in,
                              void* d_out, int out_size, void* d_ws, size_t ws_size,
                              hipStream_t stream) {
    const float* out_full = (const float*)d_in[0];  // [8192, 512]
    const float* out_1    = (const float*)d_in[1];  // [4096, 512]
    const float* out_2    = (const float*)d_in[2];  // [4096, 512]
    const int*   labels   = (const int*)d_in[3];    // [8192]
    float* loss = (float*)d_out;

    _Float16* Xf   = (_Float16*)d_ws;                                  // 8 MiB
    float*    denom = (float*)((char*)d_ws + (size_t)NROWS * DIM * 2); // 32 KiB

    hipMemsetAsync(denom, 0, NROWS * sizeof(float), stream);
    hipMemsetAsync(loss, 0, sizeof(float), stream);

    cast_kernel<<<(NROWS * DIM) / (256 * 4), 256, 0, stream>>>(out_full, Xf);

    dim3 grid(NROWS / 128, NROWS / 128);
    gemm_denom_kernel<<<grid, 256, 0, stream>>>(Xf, labels, denom);

    pos_kernel<<<128, 256, 0, stream>>>(out_1, out_2, loss);
    logdenom_kernel<<<NROWS / 256, 256, 0, stream>>>(denom, loss);
}

// Round 2
// 147.477 us; speedup vs baseline: 2.0196x; 2.0196x over previous
//
#include <hip/hip_runtime.h>
#include <stdint.h>

// SimCLR clear loss, MI355X — round 2: label-sorted block-diagonal GEMM.
// sim is masked to same-class pairs only -> sort rows by class, compute only
// the 7 diagonal class blocks (~1/5.9 of the tiles). All in sorted space;
// mean(log denom) is permutation-invariant so no inverse mapping needed.

#define NROWS 8192
#define DIM   512
#define NCLS  7
#define MAXTILES 4544     // sum T_c^2 <= maxT * sumT <= 64*71
#define GEMM_GRID 2048

typedef _Float16 f16x8 __attribute__((ext_vector_type(8)));
typedef _Float16 f16x4 __attribute__((ext_vector_type(4)));
typedef float    f32x4 __attribute__((ext_vector_type(4)));

__device__ __forceinline__ void load16_g2l(void* lds, const void* g) {
    auto* l3 = reinterpret_cast<__attribute__((address_space(3))) uint32_t*>(
        reinterpret_cast<uintptr_t>(lds));
    auto* g1 = reinterpret_cast<const __attribute__((address_space(1))) uint32_t*>(
        reinterpret_cast<uintptr_t>(g));
    __builtin_amdgcn_global_load_lds(g1, l3, 16, 0, 0);
}

// ---------------- 1. planner: histogram -> offsets -> tile table ----------------
__global__ __launch_bounds__(256) void plan_kernel(const int* __restrict__ labels,
                                                   int* __restrict__ rowbase,
                                                   int4* __restrict__ tiles,
                                                   int* __restrict__ nTiles,
                                                   float* __restrict__ denomS,
                                                   float* __restrict__ loss) {
    __shared__ int hist[NCLS];
    __shared__ int off[NCLS + 1];
    __shared__ int tb[NCLS + 1];
    const int tid = threadIdx.x;
    if (tid < NCLS) hist[tid] = 0;
    __syncthreads();
    for (int i = tid; i < NROWS; i += 256) atomicAdd(&hist[labels[i]], 1);
    __syncthreads();
    if (tid == 0) {
        int o = 0, t = 0;
        for (int c = 0; c < NCLS; ++c) {
            off[c] = o; tb[c] = t;
            rowbase[c] = o;                 // scatter counters start at class offset
            int T = (hist[c] + 127) >> 7;
            o += hist[c]; t += T * T;
        }
        off[NCLS] = o; tb[NCLS] = t;
        *nTiles = t;
        *loss = 0.f;
    }
    __syncthreads();
    const int tot = tb[NCLS];
    for (int t = tid; t < tot; t += 256) {
        int c = 0;
        while (t >= tb[c + 1]) ++c;
        int local = t - tb[c];
        int T = (hist[c] + 127) >> 7;
        int ti = local / T, tj = local - ti * T;
        tiles[t] = make_int4(off[c] + ti * 128, off[c] + tj * 128, off[c] + hist[c], 0);
    }
    for (int i = tid; i < NROWS; i += 256) denomS[i] = 0.f;
}

// ---------------- 2. wave-aggregated rank scatter ----------------
__global__ __launch_bounds__(256) void scatter_kernel(const int* __restrict__ labels,
                                                      int* __restrict__ rowbase,
                                                      int* __restrict__ rowmap) {
    const int i = blockIdx.x * 256 + threadIdx.x;
    const int lab = labels[i];
    const int lane = threadIdx.x & 63;
    const unsigned long long lt = (1ull << lane) - 1ull;
    int dest = 0;
    #pragma unroll
    for (int c = 0; c < NCLS; ++c) {
        bool mine = (lab == c);
        unsigned long long m = __ballot(mine);
        if (m) {
            int leader = __builtin_ctzll(m);
            int base = 0;
            if (lane == leader) base = atomicAdd(&rowbase[c], __builtin_popcountll(m));
            base = __shfl(base, leader, 64);
            if (mine) dest = base + __builtin_popcountll(m & lt);
        }
    }
    rowmap[dest] = i;
}

// ---------------- 3. fp32 -> f16 cast fused with permutation gather ----------------
__global__ __launch_bounds__(256) void cast_gather_kernel(const float* __restrict__ x,
                                                          const int* __restrict__ rowmap,
                                                          _Float16* __restrict__ y) {
    int gid = blockIdx.x * 256 + threadIdx.x;   // float4 index
    int row = gid >> 7;                          // 128 chunks of 4 per row
    int col = (gid & 127) << 2;
    int orig = rowmap[row];
    float4 v = *(const float4*)(x + (size_t)orig * DIM + col);
    f16x4 h;
    h[0] = (_Float16)v.x; h[1] = (_Float16)v.y;
    h[2] = (_Float16)v.z; h[3] = (_Float16)v.w;
    *(f16x4*)(y + (size_t)row * DIM + col) = h;
}

// ---------------- 4. fused GEMM + exp + mask + row-sum over class tiles ----------------
// 128x128 tile, BK=64, 4 waves (2x2 of 64x64), 16x16x32 f16 MFMA.
// LDS fragment-ordered so ds_read_b128 is conflict-free and global_load_lds
// (wave-uniform base + lane*16) lands gathers where fragment reads expect them.
__global__ __launch_bounds__(256) void gemm_denom_kernel(const _Float16* __restrict__ X,
                                                         const int4* __restrict__ tiles,
                                                         const int* __restrict__ nTiles,
                                                         float* __restrict__ denom) {
    __shared__ __align__(16) _Float16 Atile[8192];  // [2][8][64][8]
    __shared__ __align__(16) _Float16 Btile[8192];

    const int tid  = threadIdx.x;
    const int lane = tid & 63;
    const int wv   = tid >> 6;
    const int lc   = lane & 15;
    const int l8   = (lane >> 4) * 8;
    const int nT   = *nTiles;

    for (int t = blockIdx.x; t < nT; t += gridDim.x) {
        const int4 d = tiles[t];
        const int bm = d.x, bn = d.y, end = d.z;

        f32x4 acc[4][4] = {};

        for (int kb = 0; kb < DIM; kb += 64) {
            __syncthreads();  // protect LDS from previous readers
            #pragma unroll
            for (int g = 0; g < 8; ++g) {
                int grp  = wv + g * 4;            // wave-uniform
                int idx  = grp & 15;
                int kk2  = idx >> 3;
                int rg   = idx & 7;
                int row  = (grp < 16 ? bm : bn) + rg * 16 + lc;
                row = min(row, end - 1);          // partial tile: dup last row, masked later
                int kcol = kb + kk2 * 32 + l8;
                const _Float16* src = X + (size_t)row * DIM + kcol;
                _Float16* dst = (grp < 16 ? Atile : Btile) + ((kk2 * 8 + rg) * 64 + lane) * 8;
                load16_g2l(dst, src);
            }
            __syncthreads();  // vmcnt(0) drain: staged data visible

            const int rga = (wv >> 1) * 4;
            const int rgb = (wv & 1) * 4;
            #pragma unroll
            for (int kk2 = 0; kk2 < 2; ++kk2) {
                f16x8 af[4], bf[4];
                #pragma unroll
                for (int q = 0; q < 4; ++q)
                    af[q] = *(const f16x8*)&Atile[((kk2 * 8 + rga + q) * 64 + lane) * 8];
                #pragma unroll
                for (int q = 0; q < 4; ++q)
                    bf[q] = *(const f16x8*)&Btile[((kk2 * 8 + rgb + q) * 64 + lane) * 8];
                #pragma unroll
                for (int mt = 0; mt < 4; ++mt)
                    #pragma unroll
                    for (int nt = 0; nt < 4; ++nt)
                        acc[mt][nt] = __builtin_amdgcn_mfma_f32_16x16x32_f16(
                            af[mt], bf[nt], acc[mt][nt], 0, 0, 0);
            }
        }

        // epilogue: exp2(acc * 2*log2e), mask (in-class col && i!=j), row-reduce, atomic
        // C/D layout: col = lane&15, row = (lane>>4)*4 + reg   [m89/m91]
        const int row0 = bm + (wv >> 1) * 64;
        const int col0 = bn + (wv & 1) * 64;
        const int lq   = lane >> 4;
        const float cs = 2.0f * 1.4426950408889634f;  // (1/T) * log2(e)

        #pragma unroll
        for (int mt = 0; mt < 4; ++mt) {
            #pragma unroll
            for (int r = 0; r < 4; ++r) {
                int grow = row0 + mt * 16 + lq * 4 + r;
                float s = 0.f;
                #pragma unroll
                for (int nt = 0; nt < 4; ++nt) {
                    int gcol = col0 + nt * 16 + lc;
                    float e = exp2f(acc[mt][nt][r] * cs);
                    s += ((gcol < end) && (grow != gcol)) ? e : 0.f;
                }
                #pragma unroll
                for (int dd = 1; dd < 16; dd <<= 1) s += __shfl_xor(s, dd, 64);
                if (lc == 0 && grow < end) atomicAdd(&denom[grow], s);
            }
        }
    }
}

// ---------------- 5. positive-pair term ----------------
__global__ __launch_bounds__(256) void pos_kernel(const float* __restrict__ o1,
                                                  const float* __restrict__ o2,
                                                  float* __restrict__ out) {
    const int lane = threadIdx.x & 63;
    const int wave = (blockIdx.x * 256 + threadIdx.x) >> 6;  // 0..511
    float s = 0.f;
    for (int r = wave; r < 4096; r += 512) {
        const float4* a = (const float4*)(o1 + (size_t)r * DIM);
        const float4* b = (const float4*)(o2 + (size_t)r * DIM);
        float4 va = a[lane], vb = b[lane];
        s += va.x * vb.x + va.y * vb.y + va.z * vb.z + va.w * vb.w;
        va = a[lane + 64]; vb = b[lane + 64];
        s += va.x * vb.x + va.y * vb.y + va.z * vb.z + va.w * vb.w;
    }
    #pragma unroll
    for (int d = 1; d < 64; d <<= 1) s += __shfl_xor(s, d, 64);
    __shared__ float red[4];
    if (lane == 0) red[threadIdx.x >> 6] = s;
    __syncthreads();
    if (threadIdx.x == 0)
        atomicAdd(out, -(red[0] + red[1] + red[2] + red[3]) * (1.0f / 2048.0f));
}

// ---------------- 6. mean(log(denom)) ----------------
__global__ __launch_bounds__(256) void logdenom_kernel(const float* __restrict__ denom,
                                                       float* __restrict__ out) {
    int i = blockIdx.x * 256 + threadIdx.x;
    float v = __logf(denom[i]) * (1.0f / 8192.0f);
    #pragma unroll
    for (int d = 1; d < 64; d <<= 1) v += __shfl_xor(v, d, 64);
    __shared__ float red[4];
    if ((threadIdx.x & 63) == 0) red[threadIdx.x >> 6] = v;
    __syncthreads();
    if (threadIdx.x == 0) atomicAdd(out, red[0] + red[1] + red[2] + red[3]);
}

extern "C" void kernel_launch(void* const* d_in, const int* in_sizes, int n_in,
                              void* d_out, int out_size, void* d_ws, size_t ws_size,
                              hipStream_t stream) {
    const float* out_full = (const float*)d_in[0];  // [8192, 512]
    const float* out_1    = (const float*)d_in[1];  // [4096, 512]
    const float* out_2    = (const float*)d_in[2];  // [4096, 512]
    const int*   labels   = (const int*)d_in[3];    // [8192]
    float* loss = (float*)d_out;

    char* ws = (char*)d_ws;
    _Float16* Xs     = (_Float16*)ws;                                   // 8 MiB
    float*    denomS = (float*)(ws + 8388608);                          // 32 KiB
    int*      rowmap = (int*)(ws + 8421376);                            // 32 KiB
    int*      rowbase= (int*)(ws + 8454144);                            // 64 B
    int*      nTiles = (int*)(ws + 8454208);                            // 64 B
    int4*     tiles  = (int4*)(ws + 8454272);                           // 71 KiB

    plan_kernel<<<1, 256, 0, stream>>>(labels, rowbase, tiles, nTiles, denomS, loss);
    scatter_kernel<<<NROWS / 256, 256, 0, stream>>>(labels, rowbase, rowmap);
    cast_gather_kernel<<<(NROWS * DIM / 4) / 256, 256, 0, stream>>>(out_full, rowmap, Xs);

    gemm_denom_kernel<<<GEMM_GRID, 256, 0, stream>>>(Xs, tiles, nTiles, denomS);

    pos_kernel<<<128, 256, 0, stream>>>(out_1, out_2, loss);
    logdenom_kernel<<<NROWS / 256, 256, 0, stream>>>(denomS, loss);
}

// Round 3
// 139.181 us; speedup vs baseline: 2.1399x; 1.0596x over previous
//
#include <hip/hip_runtime.h>
#include <stdint.h>

// SimCLR clear loss, MI355X — round 3: label-sorted block-diagonal GEMM,
// upper-triangle tiles only (sim symmetric), pos-term folded into idle blocks.

#define NROWS 8192
#define DIM   512
#define NCLS  7
#define MAXTILES 2112     // worst case: one class -> T=64 -> T(T+1)/2 = 2080
#define GEMM_GRID 2048
#define POSB0 1536        // blocks [POSB0, POSB0+128) also compute pos partials

typedef _Float16 f16x8 __attribute__((ext_vector_type(8)));
typedef _Float16 f16x4 __attribute__((ext_vector_type(4)));
typedef float    f32x4 __attribute__((ext_vector_type(4)));

__device__ __forceinline__ void load16_g2l(void* lds, const void* g) {
    auto* l3 = reinterpret_cast<__attribute__((address_space(3))) uint32_t*>(
        reinterpret_cast<uintptr_t>(lds));
    auto* g1 = reinterpret_cast<const __attribute__((address_space(1))) uint32_t*>(
        reinterpret_cast<uintptr_t>(g));
    __builtin_amdgcn_global_load_lds(g1, l3, 16, 0, 0);
}

// ---------------- 1. planner: histogram -> offsets -> triangular tile table ----------------
__global__ __launch_bounds__(256) void plan_kernel(const int* __restrict__ labels,
                                                   int* __restrict__ rowbase,
                                                   int4* __restrict__ tiles,
                                                   int* __restrict__ nTiles,
                                                   float* __restrict__ denomS,
                                                   float* __restrict__ loss) {
    __shared__ int hist[NCLS];
    __shared__ int off[NCLS + 1];
    __shared__ int tb[NCLS + 1];
    const int tid = threadIdx.x;
    if (tid < NCLS) hist[tid] = 0;
    __syncthreads();
    for (int i = tid; i < NROWS; i += 256) atomicAdd(&hist[labels[i]], 1);
    __syncthreads();
    if (tid == 0) {
        int o = 0, t = 0;
        for (int c = 0; c < NCLS; ++c) {
            off[c] = o; tb[c] = t;
            rowbase[c] = o;
            int T = (hist[c] + 127) >> 7;
            o += hist[c]; t += T * (T + 1) / 2;
        }
        off[NCLS] = o; tb[NCLS] = t;
        *nTiles = t;
        *loss = 0.f;
    }
    __syncthreads();
    const int tot = tb[NCLS];
    for (int t = tid; t < tot; t += 256) {
        int c = 0;
        while (t >= tb[c + 1]) ++c;
        int rem = t - tb[c];
        int T = (hist[c] + 127) >> 7;
        int ti = 0;
        while (rem >= T - ti) { rem -= (T - ti); ++ti; }   // ti<=tj triangular decode
        int tj = ti + rem;
        tiles[t] = make_int4(off[c] + ti * 128, off[c] + tj * 128, off[c] + hist[c], 0);
    }
    for (int i = tid; i < NROWS; i += 256) denomS[i] = 0.f;
}

// ---------------- 2. wave-aggregated rank scatter ----------------
__global__ __launch_bounds__(256) void scatter_kernel(const int* __restrict__ labels,
                                                      int* __restrict__ rowbase,
                                                      int* __restrict__ rowmap) {
    const int i = blockIdx.x * 256 + threadIdx.x;
    const int lab = labels[i];
    const int lane = threadIdx.x & 63;
    const unsigned long long lt = (1ull << lane) - 1ull;
    int dest = 0;
    #pragma unroll
    for (int c = 0; c < NCLS; ++c) {
        bool mine = (lab == c);
        unsigned long long m = __ballot(mine);
        if (m) {
            int leader = __builtin_ctzll(m);
            int base = 0;
            if (lane == leader) base = atomicAdd(&rowbase[c], __builtin_popcountll(m));
            base = __shfl(base, leader, 64);
            if (mine) dest = base + __builtin_popcountll(m & lt);
        }
    }
    rowmap[dest] = i;
}

// ---------------- 3. fp32 -> f16 cast fused with permutation gather ----------------
__global__ __launch_bounds__(256) void cast_gather_kernel(const float* __restrict__ x,
                                                          const int* __restrict__ rowmap,
                                                          _Float16* __restrict__ y) {
    int gid = blockIdx.x * 256 + threadIdx.x;
    int row = gid >> 7;
    int col = (gid & 127) << 2;
    int orig = rowmap[row];
    float4 v = *(const float4*)(x + (size_t)orig * DIM + col);
    f16x4 h;
    h[0] = (_Float16)v.x; h[1] = (_Float16)v.y;
    h[2] = (_Float16)v.z; h[3] = (_Float16)v.w;
    *(f16x4*)(y + (size_t)row * DIM + col) = h;
}

// ---------------- 4. fused GEMM over upper-triangle class tiles + pos fold ----------------
// 128x128 tile, BK=64, 4 waves (2x2 of 64x64), 16x16x32 f16 MFMA.
// Off-diagonal tiles: row-sums -> denom[rows], col-sums -> denom[cols] (S^T reuse).
// Diagonal tiles: stage A only, feed both operands, i!=j mask.
__global__ __launch_bounds__(256) void gemm_denom_kernel(const _Float16* __restrict__ X,
                                                         const int4* __restrict__ tiles,
                                                         const int* __restrict__ nTiles,
                                                         float* __restrict__ denom,
                                                         const float* __restrict__ o1,
                                                         const float* __restrict__ o2,
                                                         float* __restrict__ loss) {
    __shared__ __align__(16) _Float16 Atile[8192];  // [2][8][64][8]
    __shared__ __align__(16) _Float16 Btile[8192];

    const int tid  = threadIdx.x;
    const int lane = tid & 63;
    const int wv   = tid >> 6;
    const int lc   = lane & 15;
    const int lq   = lane >> 4;
    const int l8   = lq * 8;
    const int nT   = *nTiles;

    for (int t = blockIdx.x; t < nT; t += gridDim.x) {
        const int4 d = tiles[t];
        const int bm = d.x, bn = d.y, end = d.z;
        const bool diag = (bm == bn);

        f32x4 acc[4][4] = {};

        for (int kb = 0; kb < DIM; kb += 64) {
            __syncthreads();
            #pragma unroll
            for (int g = 0; g < 8; ++g) {
                int grp  = wv + g * 4;            // wave-uniform
                if (diag && grp >= 16) continue;  // diag: A tile only
                int idx  = grp & 15;
                int kk2  = idx >> 3;
                int rg   = idx & 7;
                int row  = (grp < 16 ? bm : bn) + rg * 16 + lc;
                row = min(row, end - 1);          // partial tile: dup last row, masked later
                int kcol = kb + kk2 * 32 + l8;
                const _Float16* src = X + (size_t)row * DIM + kcol;
                _Float16* dst = (grp < 16 ? Atile : Btile) + ((kk2 * 8 + rg) * 64 + lane) * 8;
                load16_g2l(dst, src);
            }
            __syncthreads();

            const _Float16* Bbase = diag ? Atile : Btile;
            const int rga = (wv >> 1) * 4;
            const int rgb = (wv & 1) * 4;
            #pragma unroll
            for (int kk2 = 0; kk2 < 2; ++kk2) {
                f16x8 af[4], bf[4];
                #pragma unroll
                for (int q = 0; q < 4; ++q)
                    af[q] = *(const f16x8*)&Atile[((kk2 * 8 + rga + q) * 64 + lane) * 8];
                #pragma unroll
                for (int q = 0; q < 4; ++q)
                    bf[q] = *(const f16x8*)&Bbase[((kk2 * 8 + rgb + q) * 64 + lane) * 8];
                #pragma unroll
                for (int mt = 0; mt < 4; ++mt)
                    #pragma unroll
                    for (int nt = 0; nt < 4; ++nt)
                        acc[mt][nt] = __builtin_amdgcn_mfma_f32_16x16x32_f16(
                            af[mt], bf[nt], acc[mt][nt], 0, 0, 0);
            }
        }

        // epilogue. C/D layout: col = lane&15, row = (lane>>4)*4 + reg   [m89/m91]
        const int row0 = bm + (wv >> 1) * 64;
        const int col0 = bn + (wv & 1) * 64;
        const float cs = 2.0f * 1.4426950408889634f;  // (1/T) * log2(e)

        float colsum[4] = {0.f, 0.f, 0.f, 0.f};
        #pragma unroll
        for (int mt = 0; mt < 4; ++mt) {
            #pragma unroll
            for (int r = 0; r < 4; ++r) {
                int grow = row0 + mt * 16 + lq * 4 + r;
                float s = 0.f;
                #pragma unroll
                for (int nt = 0; nt < 4; ++nt) {
                    int gcol = col0 + nt * 16 + lc;
                    float e = exp2f(acc[mt][nt][r] * cs);
                    bool ok = (gcol < end) && (!diag || (grow != gcol));
                    e = ok ? e : 0.f;
                    s += e;
                    colsum[nt] += e;
                }
                #pragma unroll
                for (int dd = 1; dd < 16; dd <<= 1) s += __shfl_xor(s, dd, 64);
                if (lc == 0 && grow < end) atomicAdd(&denom[grow], s);
            }
        }
        if (!diag) {  // transpose reuse: col-sums feed the mirrored tile's rows
            #pragma unroll
            for (int nt = 0; nt < 4; ++nt) {
                float c2 = colsum[nt];
                c2 += __shfl_xor(c2, 16, 64);
                c2 += __shfl_xor(c2, 32, 64);
                int gcol = col0 + nt * 16 + lc;
                if (lq == 0 && gcol < end) atomicAdd(&denom[gcol], c2);
            }
        }
    }

    // ---- pos fold: blocks [POSB0, POSB0+128) compute -mean(log pos) partials ----
    if (blockIdx.x >= POSB0 && blockIdx.x < POSB0 + 128) {
        const int wave = (blockIdx.x - POSB0) * 4 + wv;  // 0..511
        float s = 0.f;
        for (int r = wave; r < 4096; r += 512) {
            const float4* a = (const float4*)(o1 + (size_t)r * DIM);
            const float4* b = (const float4*)(o2 + (size_t)r * DIM);
            float4 va = a[lane], vb = b[lane];
            s += va.x * vb.x + va.y * vb.y + va.z * vb.z + va.w * vb.w;
            va = a[lane + 64]; vb = b[lane + 64];
            s += va.x * vb.x + va.y * vb.y + va.z * vb.z + va.w * vb.w;
        }
        #pragma unroll
        for (int dd = 1; dd < 64; dd <<= 1) s += __shfl_xor(s, dd, 64);
        __shared__ float red[4];
        if (lane == 0) red[wv] = s;
        __syncthreads();
        if (tid == 0)
            atomicAdd(loss, -(red[0] + red[1] + red[2] + red[3]) * (1.0f / 2048.0f));
    }
}

// ---------------- 5. mean(log(denom)) ----------------
__global__ __launch_bounds__(256) void logdenom_kernel(const float* __restrict__ denom,
                                                       float* __restrict__ out) {
    int i = blockIdx.x * 256 + threadIdx.x;
    float v = __logf(denom[i]) * (1.0f / 8192.0f);
    #pragma unroll
    for (int d = 1; d < 64; d <<= 1) v += __shfl_xor(v, d, 64);
    __shared__ float red[4];
    if ((threadIdx.x & 63) == 0) red[threadIdx.x >> 6] = v;
    __syncthreads();
    if (threadIdx.x == 0) atomicAdd(out, red[0] + red[1] + red[2] + red[3]);
}

extern "C" void kernel_launch(void* const* d_in, const int* in_sizes, int n_in,
                              void* d_out, int out_size, void* d_ws, size_t ws_size,
                              hipStream_t stream) {
    const float* out_full = (const float*)d_in[0];  // [8192, 512]
    const float* out_1    = (const float*)d_in[1];  // [4096, 512]
    const float* out_2    = (const float*)d_in[2];  // [4096, 512]
    const int*   labels   = (const int*)d_in[3];    // [8192]
    float* loss = (float*)d_out;

    char* ws = (char*)d_ws;
    _Float16* Xs     = (_Float16*)ws;                                   // 8 MiB
    float*    denomS = (float*)(ws + 8388608);                          // 32 KiB
    int*      rowmap = (int*)(ws + 8421376);                            // 32 KiB
    int*      rowbase= (int*)(ws + 8454144);                            // 64 B
    int*      nTiles = (int*)(ws + 8454208);                            // 64 B
    int4*     tiles  = (int4*)(ws + 8454272);                           // 33 KiB

    plan_kernel<<<1, 256, 0, stream>>>(labels, rowbase, tiles, nTiles, denomS, loss);
    scatter_kernel<<<NROWS / 256, 256, 0, stream>>>(labels, rowbase, rowmap);
    cast_gather_kernel<<<(NROWS * DIM / 4) / 256, 256, 0, stream>>>(out_full, rowmap, Xs);

    gemm_denom_kernel<<<GEMM_GRID, 256, 0, stream>>>(Xs, tiles, nTiles, denomS,
                                                     out_1, out_2, loss);

    logdenom_kernel<<<NROWS / 256, 256, 0, stream>>>(denomS, loss);
}

// Round 4
// 123.128 us; speedup vs baseline: 2.4189x; 1.1304x over previous
//
#include <hip/hip_runtime.h>
#include <stdint.h>

// SimCLR clear loss, MI355X — round 4: 64x64 tiles for occupancy (latency-bound
// regime), atomic-free fused scatter+cast via plan-computed segment bases.

#define NROWS 8192
#define DIM   512
#define NCLS  7
#define GEMM_GRID 2048
#define POSB0 1920        // blocks [POSB0, 2048) also compute pos partials

typedef _Float16 f16x8 __attribute__((ext_vector_type(8)));
typedef _Float16 f16x4 __attribute__((ext_vector_type(4)));
typedef float    f32x4 __attribute__((ext_vector_type(4)));

__device__ __forceinline__ void load16_g2l(void* lds, const void* g) {
    auto* l3 = reinterpret_cast<__attribute__((address_space(3))) uint32_t*>(
        reinterpret_cast<uintptr_t>(lds));
    auto* g1 = reinterpret_cast<const __attribute__((address_space(1))) uint32_t*>(
        reinterpret_cast<uintptr_t>(g));
    __builtin_amdgcn_global_load_lds(g1, l3, 16, 0, 0);
}

// ---------------- 1. planner ----------------
// Per-64-row-segment class counts -> wavebase[128][7] (exclusive prefix + class
// offset), class offsets, triangular 64-tile table, denom/loss zero.
__global__ __launch_bounds__(256) void plan_kernel(const int* __restrict__ labels,
                                                   int* __restrict__ wavebase,
                                                   int4* __restrict__ tiles,
                                                   int* __restrict__ nTiles,
                                                   float* __restrict__ denomS,
                                                   float* __restrict__ loss) {
    __shared__ int cnt[128][NCLS];
    __shared__ int pref[128][NCLS];
    __shared__ int hist[NCLS];
    __shared__ int off[NCLS + 1];
    __shared__ int tb[NCLS + 1];
    const int tid = threadIdx.x;

    if (tid < 128) {
        int c0 = 0, c1 = 0, c2 = 0, c3 = 0, c4 = 0, c5 = 0, c6 = 0;
        const int base = tid * 64;
        for (int j = 0; j < 64; ++j) {
            int l = labels[base + j];
            c0 += (l == 0); c1 += (l == 1); c2 += (l == 2); c3 += (l == 3);
            c4 += (l == 4); c5 += (l == 5); c6 += (l == 6);
        }
        cnt[tid][0] = c0; cnt[tid][1] = c1; cnt[tid][2] = c2; cnt[tid][3] = c3;
        cnt[tid][4] = c4; cnt[tid][5] = c5; cnt[tid][6] = c6;
    }
    __syncthreads();
    if (tid < NCLS) {
        int run = 0;
        for (int s = 0; s < 128; ++s) { pref[s][tid] = run; run += cnt[s][tid]; }
        hist[tid] = run;
    }
    __syncthreads();
    if (tid == 0) {
        int o = 0, t = 0;
        for (int c = 0; c < NCLS; ++c) {
            off[c] = o; tb[c] = t;
            int T = (hist[c] + 63) >> 6;
            o += hist[c]; t += T * (T + 1) / 2;
        }
        off[NCLS] = o; tb[NCLS] = t;
        *nTiles = t;
        *loss = 0.f;
    }
    __syncthreads();
    for (int i = tid; i < 128 * NCLS; i += 256) {
        int s = i / NCLS, c = i - s * NCLS;
        wavebase[i] = off[c] + pref[s][c];
    }
    const int tot = tb[NCLS];
    for (int t = tid; t < tot; t += 256) {
        int c = 0;
        while (t >= tb[c + 1]) ++c;
        int rem = t - tb[c];
        int T = (hist[c] + 63) >> 6;
        int ti = 0;
        while (rem >= T - ti) { rem -= (T - ti); ++ti; }   // ti<=tj
        int tj = ti + rem;
        tiles[t] = make_int4(off[c] + ti * 64, off[c] + tj * 64, off[c] + hist[c], 0);
    }
    for (int i = tid; i < NROWS; i += 256) denomS[i] = 0.f;
}

// ---------------- 2. fused scatter + fp32->f16 cast (atomic-free) ----------------
// Wave handles one row; in-segment rank via ballot, dest = wavebase + rank.
__global__ __launch_bounds__(256) void scatter_cast_kernel(const float* __restrict__ x,
                                                           const int* __restrict__ labels,
                                                           const int* __restrict__ wavebase,
                                                           _Float16* __restrict__ y) {
    const int wv   = threadIdx.x >> 6;
    const int lane = threadIdx.x & 63;
    const int row  = blockIdx.x * 4 + wv;        // 0..8191
    const int seg  = row >> 6;
    const int lab  = labels[seg * 64 + lane];    // label of segment-row `lane`
    unsigned long long m0 = __ballot(lab == 0), m1 = __ballot(lab == 1),
                       m2 = __ballot(lab == 2), m3 = __ballot(lab == 3),
                       m4 = __ballot(lab == 4), m5 = __ballot(lab == 5),
                       m6 = __ballot(lab == 6);
    unsigned long long mymask =
        lab == 0 ? m0 : lab == 1 ? m1 : lab == 2 ? m2 : lab == 3 ? m3 :
        lab == 4 ? m4 : lab == 5 ? m5 : m6;
    const unsigned long long lt = (1ull << lane) - 1ull;
    int dest_lane = wavebase[seg * NCLS + lab] + __builtin_popcountll(mymask & lt);
    int dest = __shfl(dest_lane, row & 63, 64);  // dest of THIS wave's row

    const float4* src = (const float4*)(x + (size_t)row * DIM);
    _Float16* dst = y + (size_t)dest * DIM;
    #pragma unroll
    for (int p = 0; p < 2; ++p) {
        float4 v = src[lane + p * 64];
        f16x4 h;
        h[0] = (_Float16)v.x; h[1] = (_Float16)v.y;
        h[2] = (_Float16)v.z; h[3] = (_Float16)v.w;
        *(f16x4*)(dst + (lane + p * 64) * 4) = h;
    }
}

// ---------------- 3. fused GEMM over upper-triangle 64x64 class tiles + pos ----------------
// 4 waves, each a 32x32 quadrant (acc 2x2 of f32x4). LDS fragment-ordered
// [2][4][64][8]; off-diag tiles emit row-sums AND col-sums (S^T reuse);
// diag tiles stage A only and mask i!=j.
__global__ __launch_bounds__(256, 6) void gemm_denom_kernel(const _Float16* __restrict__ X,
                                                            const int4* __restrict__ tiles,
                                                            const int* __restrict__ nTiles,
                                                            float* __restrict__ denom,
                                                            const float* __restrict__ o1,
                                                            const float* __restrict__ o2,
                                                            float* __restrict__ loss) {
    __shared__ __align__(16) _Float16 Atile[4096];  // [2][4][64][8] = 8 KiB
    __shared__ __align__(16) _Float16 Btile[4096];

    const int tid  = threadIdx.x;
    const int lane = tid & 63;
    const int wv   = tid >> 6;
    const int lc   = lane & 15;
    const int lq   = lane >> 4;
    const int l8   = lq * 8;
    const int nT   = *nTiles;

    for (int t = blockIdx.x; t < nT; t += gridDim.x) {
        const int4 d = tiles[t];
        const int bm = d.x, bn = d.y, end = d.z;
        const bool diag = (bm == bn);

        f32x4 acc[2][2] = {};

        for (int kb = 0; kb < DIM; kb += 64) {
            __syncthreads();
            #pragma unroll
            for (int g = 0; g < 4; ++g) {
                int grp = wv + g * 4;             // 0..15, wave-uniform
                if (diag && grp >= 8) continue;   // diag: A tile only
                int idx = grp & 7;
                int kk2 = idx >> 2;
                int rg  = idx & 3;
                int row = (grp < 8 ? bm : bn) + rg * 16 + lc;
                row = min(row, end - 1);          // partial: dup last row, masked later
                int kcol = kb + kk2 * 32 + l8;
                const _Float16* src = X + (size_t)row * DIM + kcol;
                _Float16* dst = (grp < 8 ? Atile : Btile) + ((kk2 * 4 + rg) * 64 + lane) * 8;
                load16_g2l(dst, src);
            }
            __syncthreads();

            const _Float16* Bbase = diag ? Atile : Btile;
            const int rga = (wv >> 1) * 2;
            const int rgb = (wv & 1) * 2;
            #pragma unroll
            for (int kk2 = 0; kk2 < 2; ++kk2) {
                f16x8 af[2], bf[2];
                #pragma unroll
                for (int q = 0; q < 2; ++q)
                    af[q] = *(const f16x8*)&Atile[((kk2 * 4 + rga + q) * 64 + lane) * 8];
                #pragma unroll
                for (int q = 0; q < 2; ++q)
                    bf[q] = *(const f16x8*)&Bbase[((kk2 * 4 + rgb + q) * 64 + lane) * 8];
                #pragma unroll
                for (int mt = 0; mt < 2; ++mt)
                    #pragma unroll
                    for (int nt = 0; nt < 2; ++nt)
                        acc[mt][nt] = __builtin_amdgcn_mfma_f32_16x16x32_f16(
                            af[mt], bf[nt], acc[mt][nt], 0, 0, 0);
            }
        }

        // epilogue. C/D: col = lane&15, row = (lane>>4)*4 + reg   [m89/m91]
        const int row0 = bm + (wv >> 1) * 32;
        const int col0 = bn + (wv & 1) * 32;
        const float cs = 2.0f * 1.4426950408889634f;  // (1/T)*log2(e)

        float colsum[2] = {0.f, 0.f};
        #pragma unroll
        for (int mt = 0; mt < 2; ++mt) {
            #pragma unroll
            for (int r = 0; r < 4; ++r) {
                int grow = row0 + mt * 16 + lq * 4 + r;
                float s = 0.f;
                #pragma unroll
                for (int nt = 0; nt < 2; ++nt) {
                    int gcol = col0 + nt * 16 + lc;
                    float e = exp2f(acc[mt][nt][r] * cs);
                    bool ok = (gcol < end) && (!diag || (grow != gcol));
                    e = ok ? e : 0.f;
                    s += e;
                    colsum[nt] += e;
                }
                #pragma unroll
                for (int dd = 1; dd < 16; dd <<= 1) s += __shfl_xor(s, dd, 64);
                if (lc == 0 && grow < end) atomicAdd(&denom[grow], s);
            }
        }
        if (!diag) {  // mirrored tile's row-sums (row blocks of off-diag are always full)
            #pragma unroll
            for (int nt = 0; nt < 2; ++nt) {
                float c2 = colsum[nt];
                c2 += __shfl_xor(c2, 16, 64);
                c2 += __shfl_xor(c2, 32, 64);
                int gcol = col0 + nt * 16 + lc;
                if (lq == 0 && gcol < end) atomicAdd(&denom[gcol], c2);
            }
        }
    }

    // ---- pos fold on trailing blocks ----
    if (blockIdx.x >= POSB0) {
        const int wave = (blockIdx.x - POSB0) * 4 + wv;  // 0..511
        float s = 0.f;
        for (int r = wave; r < 4096; r += 512) {
            const float4* a = (const float4*)(o1 + (size_t)r * DIM);
            const float4* b = (const float4*)(o2 + (size_t)r * DIM);
            float4 va = a[lane], vb = b[lane];
            s += va.x * vb.x + va.y * vb.y + va.z * vb.z + va.w * vb.w;
            va = a[lane + 64]; vb = b[lane + 64];
            s += va.x * vb.x + va.y * vb.y + va.z * vb.z + va.w * vb.w;
        }
        #pragma unroll
        for (int dd = 1; dd < 64; dd <<= 1) s += __shfl_xor(s, dd, 64);
        __shared__ float red[4];
        if (lane == 0) red[wv] = s;
        __syncthreads();
        if (tid == 0)
            atomicAdd(loss, -(red[0] + red[1] + red[2] + red[3]) * (1.0f / 2048.0f));
    }
}

// ---------------- 4. mean(log(denom)) ----------------
__global__ __launch_bounds__(256) void logdenom_kernel(const float* __restrict__ denom,
                                                       float* __restrict__ out) {
    int i = blockIdx.x * 256 + threadIdx.x;
    float v = __logf(denom[i]) * (1.0f / 8192.0f);
    #pragma unroll
    for (int d = 1; d < 64; d <<= 1) v += __shfl_xor(v, d, 64);
    __shared__ float red[4];
    if ((threadIdx.x & 63) == 0) red[threadIdx.x >> 6] = v;
    __syncthreads();
    if (threadIdx.x == 0) atomicAdd(out, red[0] + red[1] + red[2] + red[3]);
}

extern "C" void kernel_launch(void* const* d_in, const int* in_sizes, int n_in,
                              void* d_out, int out_size, void* d_ws, size_t ws_size,
                              hipStream_t stream) {
    const float* out_full = (const float*)d_in[0];  // [8192, 512]
    const float* out_1    = (const float*)d_in[1];  // [4096, 512]
    const float* out_2    = (const float*)d_in[2];  // [4096, 512]
    const int*   labels   = (const int*)d_in[3];    // [8192]
    float* loss = (float*)d_out;

    char* ws = (char*)d_ws;
    _Float16* Xs       = (_Float16*)ws;                    // 8 MiB
    float*    denomS   = (float*)(ws + 8388608);           // 32 KiB
    int*      wavebase = (int*)(ws + 8421376);             // 3.5 KiB
    int*      nTiles   = (int*)(ws + 8425472);             // 64 B
    int4*     tiles    = (int4*)(ws + 8425536);            // <=129 KiB (worst case)

    plan_kernel<<<1, 256, 0, stream>>>(labels, wavebase, tiles, nTiles, denomS, loss);
    scatter_cast_kernel<<<NROWS / 4, 256, 0, stream>>>(out_full, labels, wavebase, Xs);

    gemm_denom_kernel<<<GEMM_GRID, 256, 0, stream>>>(Xs, tiles, nTiles, denomS,
                                                     out_1, out_2, loss);

    logdenom_kernel<<<NROWS / 256, 256, 0, stream>>>(denomS, loss);
}